// Round 4
// baseline (190.878 us; speedup 1.0000x reference)
//
#include <hip/hip_runtime.h>
#include <hip/hip_bf16.h>

// Problem constants: B=8, N=256, D=300, P=128, V=50001
#define NB 8
#define NN 256
#define DD 300
#define PP 128
#define OFF_S (NB * NN * NN)            // 524288  start-head element offset
#define OFF_E (NB * NN * NN + NB * NN)  // 526336  end-head element offset

typedef unsigned short u16;

__device__ __forceinline__ float bf2f(u16 u) {
    union { unsigned int i; float f; } v;
    v.i = ((unsigned int)u) << 16;
    return v.f;
}
__device__ __forceinline__ u16 f2bf(float f) {
    union { float f; unsigned int i; } v;
    v.f = f;
    unsigned int lsb = (v.i >> 16) & 1u;
    v.i += 0x7fffu + lsb;   // round-to-nearest-even
    return (u16)(v.i >> 16);
}

template<bool BF>
__device__ __forceinline__ float4 ld4(const void* base, int idx) {
    if (BF) {
        ushort4 e = *(const ushort4*)((const u16*)base + idx);
        return make_float4(bf2f(e.x), bf2f(e.y), bf2f(e.z), bf2f(e.w));
    } else {
        return *(const float4*)((const float*)base + idx);
    }
}
template<bool BF>
__device__ __forceinline__ float ld1(const void* base, int idx) {
    return BF ? bf2f(((const u16*)base)[idx]) : ((const float*)base)[idx];
}
template<bool BF>
__device__ __forceinline__ void st1(void* base, int idx, float v) {
    if (BF) ((u16*)base)[idx] = f2bf(v);
    else    ((float*)base)[idx] = v;
}

// ---------------------------------------------------------------------------
// Detector (verbatim from the passing R2 kernel): bf16 vs f32 via low-u16
// plausibility of the first 256 words of emb.
// ---------------------------------------------------------------------------
extern "C" __global__ void detect_kernel(const unsigned int* __restrict__ embU,
                                         int* __restrict__ flag) {
    int lane = threadIdx.x;  // 64 threads
    int cnt = 0;
    for (int i = lane; i < 256; i += 64) {
        unsigned int w = embU[i];
        union { unsigned int u; float f; } v;
        v.u = (w & 0xFFFFu) << 16;
        float a = fabsf(v.f);
        if (a == 0.f || (a >= 0.00390625f && a <= 256.f)) cnt++;
    }
    #pragma unroll
    for (int off = 32; off; off >>= 1) cnt += __shfl_down(cnt, off, 64);
    if (lane == 0) *flag = (cnt >= 128) ? 1 : 0;
}

// ---------------------------------------------------------------------------
// Kernel A: per-token features. 4 tokens/block (was 8), grid 512 (was 256).
// 256 thr = (p in [0,128)) x (k-half in {0,1}). Same math as the R2-passing
// kernel, just a finer grid for occupancy.
// ---------------------------------------------------------------------------
template<bool BF>
__device__ __forceinline__ void tok_body(
    const int* __restrict__ sent, const void* __restrict__ emb,
    const void* __restrict__ Wl,  const void* __restrict__ bl,
    const void* __restrict__ Wr,
    const void* __restrict__ Ws1, const void* __restrict__ bs1,
    const void* __restrict__ Ws2, const void* __restrict__ bs2,
    const void* __restrict__ We1, const void* __restrict__ be1,
    const void* __restrict__ We2, const void* __restrict__ be2,
    float* __restrict__ leftT, float* __restrict__ rightW,
    void* __restrict__ out,
    float (*sx)[304], float (*redS)[128], float (*redE)[128])
{
    const int tid = threadIdx.x;
    const int t0  = blockIdx.x * 4;

    // Stage 4 embedding rows (-> f32 LDS). 300 4-elem chunks.
    for (int c = tid; c < 300; c += 256) {
        int t = c / 75;
        int q = c - t * 75;
        int idx = sent[t0 + t];
        float4 f = ld4<BF>(emb, idx * DD + (q << 2));
        *(float4*)&sx[t][q << 2] = f;
    }
    __syncthreads();

    const int p     = tid >> 1;
    const int kh    = tid & 1;
    const int based = kh * 152;      // K=300 split into 152 + 148 (both %4==0)
    const int nch   = 38 - kh;

    float accL[4], accR[4], accS[4], accE[4];
    #pragma unroll
    for (int t = 0; t < 4; ++t) { accL[t]=0.f; accR[t]=0.f; accS[t]=0.f; accE[t]=0.f; }

    const int wbase = p * DD + based;

    for (int c = 0; c < nch; ++c) {
        const int d4 = c << 2;
        float4 a = ld4<BF>(Wl,  wbase + d4);
        float4 r = ld4<BF>(Wr,  wbase + d4);
        float4 s = ld4<BF>(Ws1, wbase + d4);
        float4 e = ld4<BF>(We1, wbase + d4);
        #pragma unroll
        for (int t = 0; t < 4; ++t) {
            float4 xv = *(const float4*)&sx[t][based + d4];  // LDS broadcast
            accL[t] = fmaf(xv.x, a.x, accL[t]);
            accL[t] = fmaf(xv.y, a.y, accL[t]);
            accL[t] = fmaf(xv.z, a.z, accL[t]);
            accL[t] = fmaf(xv.w, a.w, accL[t]);
            accR[t] = fmaf(xv.x, r.x, accR[t]);
            accR[t] = fmaf(xv.y, r.y, accR[t]);
            accR[t] = fmaf(xv.z, r.z, accR[t]);
            accR[t] = fmaf(xv.w, r.w, accR[t]);
            accS[t] = fmaf(xv.x, s.x, accS[t]);
            accS[t] = fmaf(xv.y, s.y, accS[t]);
            accS[t] = fmaf(xv.z, s.z, accS[t]);
            accS[t] = fmaf(xv.w, s.w, accS[t]);
            accE[t] = fmaf(xv.x, e.x, accE[t]);
            accE[t] = fmaf(xv.y, e.y, accE[t]);
            accE[t] = fmaf(xv.z, e.z, accE[t]);
            accE[t] = fmaf(xv.w, e.w, accE[t]);
        }
    }

    // Combine the two K-halves: lanes (2p, 2p+1) adjacent in the wave.
    #pragma unroll
    for (int t = 0; t < 4; ++t) {
        accL[t] += __shfl_xor(accL[t], 1, 64);
        accR[t] += __shfl_xor(accR[t], 1, 64);
        accS[t] += __shfl_xor(accS[t], 1, 64);
        accE[t] += __shfl_xor(accE[t], 1, 64);
    }

    if (kh == 0) {
        float blp  = ld1<BF>(bl,  p);
        float bs1p = ld1<BF>(bs1, p);
        float ws2p = ld1<BF>(Ws2, p);
        #pragma unroll
        for (int t = 0; t < 4; ++t) {
            int tg = t0 + t;
            int bb = tg >> 8;
            int jj = tg & 255;
            leftT[((size_t)bb * PP + p) * NN + jj] = accL[t] + blp;
            rightW[(size_t)tg * PP + p]            = accR[t];
            redS[t][p] = fmaxf(accS[t] + bs1p, 0.f) * ws2p;
        }
    } else {
        float be1p = ld1<BF>(be1, p);
        float we2p = ld1<BF>(We2, p);
        #pragma unroll
        for (int t = 0; t < 4; ++t) {
            redE[t][p] = fmaxf(accE[t] + be1p, 0.f) * we2p;
        }
    }
    __syncthreads();

    // start/end reduction over p: one full wave per token (t = wave id).
    const int t = tid >> 6;
    const int l = tid & 63;
    float vs = redS[t][l] + redS[t][l + 64];
    float ve = redE[t][l] + redE[t][l + 64];
    #pragma unroll
    for (int off = 32; off; off >>= 1) {
        vs += __shfl_down(vs, off, 64);
        ve += __shfl_down(ve, off, 64);
    }
    if (l == 0) {
        st1<BF>(out, OFF_S + t0 + t, vs + ld1<BF>(bs2, 0));
        st1<BF>(out, OFF_E + t0 + t, ve + ld1<BF>(be2, 0));
    }
}

extern "C" __global__ void __launch_bounds__(256)
tok_kernel(const int* __restrict__ sent, const void* __restrict__ emb,
           const void* __restrict__ Wl,  const void* __restrict__ bl,
           const void* __restrict__ Wr,
           const void* __restrict__ Ws1, const void* __restrict__ bs1,
           const void* __restrict__ Ws2, const void* __restrict__ bs2,
           const void* __restrict__ We1, const void* __restrict__ be1,
           const void* __restrict__ We2, const void* __restrict__ be2,
           float* __restrict__ leftT, float* __restrict__ rightW,
           void* __restrict__ out, const int* __restrict__ flag)
{
    __shared__ float sx[4][304];
    __shared__ float redS[4][128];
    __shared__ float redE[4][128];
    if (*flag) {
        tok_body<true >(sent, emb, Wl, bl, Wr, Ws1, bs1, Ws2, bs2,
                        We1, be1, We2, be2, leftT, rightW, out, sx, redS, redE);
    } else {
        tok_body<false>(sent, emb, Wl, bl, Wr, Ws1, bs1, Ws2, bs2,
                        We1, be1, We2, be2, leftT, rightW, out, sx, redS, redE);
    }
}

// ---------------------------------------------------------------------------
// Kernel B: bigram[b,i,j] = sum_p relu(left[b,j,p] + right[b,i,p])*Wo[p] + bo
// 2 i's/block (was 4), grid 1024 (was 512) for occupancy. Thread = j.
// ---------------------------------------------------------------------------
extern "C" __global__ void __launch_bounds__(256)
big_kernel(const float* __restrict__ leftT, const float* __restrict__ rightW,
           const void* __restrict__ Wo, const void* __restrict__ bo,
           void* __restrict__ outB, const int* __restrict__ flag)
{
    __shared__ float sR[2][128];
    __shared__ float sWo[128];
    const int  tid = threadIdx.x;
    const int  b   = blockIdx.x >> 7;
    const int  i0  = (blockIdx.x & 127) << 1;
    const bool bf  = (*flag != 0);

    if (tid < 128) sWo[tid] = bf ? bf2f(((const u16*)Wo)[tid])
                                 : ((const float*)Wo)[tid];
    {
        int i = tid >> 7, pp = tid & 127;   // 256 threads cover sR[2][128]
        sR[i][pp] = rightW[((size_t)(b * NN + i0 + i)) * PP + pp];
    }
    __syncthreads();

    const int j = tid;
    const float* lp = leftT + (size_t)b * PP * NN + j;
    float acc0 = 0.f, acc1 = 0.f;
    #pragma unroll 8
    for (int p = 0; p < 128; ++p) {
        float lv = lp[(size_t)p * NN];    // coalesced across j
        float wo = sWo[p];
        acc0 = fmaf(fmaxf(lv + sR[0][p], 0.f), wo, acc0);
        acc1 = fmaf(fmaxf(lv + sR[1][p], 0.f), wo, acc1);
    }
    float bov = bf ? bf2f(((const u16*)bo)[0]) : ((const float*)bo)[0];
    size_t ob = ((size_t)(b * NN + i0)) * NN + j;
    if (bf) {
        u16* o = (u16*)outB;
        o[ob]      = f2bf(acc0 + bov);
        o[ob + NN] = f2bf(acc1 + bov);
    } else {
        float* o = (float*)outB;
        o[ob]      = acc0 + bov;
        o[ob + NN] = acc1 + bov;
    }
}

extern "C" void kernel_launch(void* const* d_in, const int* in_sizes, int n_in,
                              void* d_out, int out_size, void* d_ws, size_t ws_size,
                              hipStream_t stream) {
    const int*  sent = (const int*)d_in[0];
    const void* emb  = d_in[1];
    const void* Wl   = d_in[2];
    const void* bl   = d_in[3];
    const void* Wr   = d_in[4];
    const void* Wo   = d_in[5];
    const void* bo   = d_in[6];
    const void* Ws1  = d_in[7];
    const void* bs1  = d_in[8];
    const void* Ws2  = d_in[9];
    const void* bs2  = d_in[10];
    const void* We1  = d_in[11];
    const void* be1  = d_in[12];
    const void* We2  = d_in[13];
    const void* be2  = d_in[14];

    // Workspace layout identical to the passing R2 kernel:
    // [flag 4B, pad to 1KB][leftT 1MB f32][rightW 1MB f32]
    int*   flag   = (int*)d_ws;
    float* leftT  = (float*)((char*)d_ws + 1024);
    float* rightW = leftT + (size_t)NB * PP * NN;

    hipLaunchKernelGGL(detect_kernel, dim3(1), dim3(64), 0, stream,
                       (const unsigned int*)emb, flag);
    hipLaunchKernelGGL(tok_kernel, dim3(512), dim3(256), 0, stream,
                       sent, emb, Wl, bl, Wr, Ws1, bs1, Ws2, bs2,
                       We1, be1, We2, be2, leftT, rightW, d_out, flag);
    hipLaunchKernelGGL(big_kernel, dim3(1024), dim3(256), 0, stream,
                       leftT, rightW, Wo, bo, d_out, flag);
}

// Round 7
// 163.795 us; speedup vs baseline: 1.1653x; 1.1653x over previous
//
#include <hip/hip_runtime.h>

// Problem constants: B=8, N=256, D=300, P=128, V=50001
#define NB 8
#define NN 256
#define DD 300
#define PP 128
#define NC 512                          // concat cols = [Wl|Wr|Ws1|We1]
#define OFF_S (NB * NN * NN)            // 524288  start-head element offset
#define OFF_E (NB * NN * NN + NB * NN)  // 526336  end-head element offset

typedef unsigned short u16;
typedef unsigned int   u32;

__device__ __forceinline__ float bf2f(u16 u) {
    union { u32 i; float f; } v;
    v.i = ((u32)u) << 16;
    return v.f;
}
__device__ __forceinline__ u16 f2bf(float f) {
    union { float f; u32 i; } v;
    v.f = f;
    u32 lsb = (v.i >> 16) & 1u;
    v.i += 0x7fffu + lsb;   // round-to-nearest-even
    return (u16)(v.i >> 16);
}

template<bool BF>
__device__ __forceinline__ float4 ld4(const void* base, int idx) {
    if (BF) {
        ushort4 e = *(const ushort4*)((const u16*)base + idx);
        return make_float4(bf2f(e.x), bf2f(e.y), bf2f(e.z), bf2f(e.w));
    } else {
        return *(const float4*)((const float*)base + idx);
    }
}
template<bool BF>
__device__ __forceinline__ float ld1(const void* base, int idx) {
    return BF ? bf2f(((const u16*)base)[idx]) : ((const float*)base)[idx];
}
template<bool BF>
__device__ __forceinline__ void st1(void* base, int idx, float v) {
    if (BF) ((u16*)base)[idx] = f2bf(v);
    else    ((float*)base)[idx] = v;
}

// ---------------------------------------------------------------------------
// Detector (verbatim from passing R2/R4).
// ---------------------------------------------------------------------------
extern "C" __global__ void detect_kernel(const u32* __restrict__ embU,
                                         int* __restrict__ flag) {
    int lane = threadIdx.x;  // 64 threads
    int cnt = 0;
    for (int i = lane; i < 256; i += 64) {
        u32 w = embU[i];
        union { u32 u; float f; } v;
        v.u = (w & 0xFFFFu) << 16;
        float a = fabsf(v.f);
        if (a == 0.f || (a >= 0.00390625f && a <= 256.f)) cnt++;
    }
    #pragma unroll
    for (int off = 32; off; off >>= 1) cnt += __shfl_down(cnt, off, 64);
    if (lane == 0) *flag = (cnt >= 128) ? 1 : 0;
}

// ---------------------------------------------------------------------------
// prep: WTf[k][c] = (float)Wcat[c][k], k-major f32 transpose of the concat
// [Wl|Wr|Ws1|We1]. Makes tok's weight loads coalesced (float2 per lane,
// 512B contiguous per wave instead of 64 scattered lines).
// Grid 16 x 256; 32-col tile, pitch 301 (stride 301%32=13: conflict-free
// transposed reads).
// ---------------------------------------------------------------------------
template<bool BF>
__device__ __forceinline__ void prep_body(
    const void* __restrict__ Wl, const void* __restrict__ Wr,
    const void* __restrict__ Ws1, const void* __restrict__ We1,
    float* __restrict__ WTf, float (*tile)[301])
{
    const int tid = threadIdx.x;
    const int c0  = blockIdx.x * 32;

    for (int e = tid; e < 32 * 75; e += 256) {       // row-major reads
        int r = e / 75;
        int q = e - r * 75;
        int c = c0 + r;
        const void* src = (c < 128) ? Wl : (c < 256) ? Wr
                        : (c < 384) ? Ws1 : We1;
        float4 f = ld4<BF>(src, (c & 127) * DD + 4 * q);
        tile[r][4 * q + 0] = f.x;
        tile[r][4 * q + 1] = f.y;
        tile[r][4 * q + 2] = f.z;
        tile[r][4 * q + 3] = f.w;
    }
    __syncthreads();
    for (int e = tid; e < 300 * 32; e += 256) {      // k-major writes
        int k = e >> 5;
        int c = e & 31;
        WTf[(size_t)k * NC + c0 + c] = tile[c][k];
    }
}

extern "C" __global__ void __launch_bounds__(256)
prep_kernel(const void* __restrict__ Wl, const void* __restrict__ Wr,
            const void* __restrict__ Ws1, const void* __restrict__ We1,
            float* __restrict__ WTf, const int* __restrict__ flag)
{
    __shared__ float tile[32][301];
    if (*flag) prep_body<true >(Wl, Wr, Ws1, We1, WTf, tile);
    else       prep_body<false>(Wl, Wr, Ws1, We1, WTf, tile);
}

// ---------------------------------------------------------------------------
// tok: per-token features from k-major f32 weights (dtype-neutral core).
// Grid 256 blocks (8 tokens) x 256 thr. Wave = matrix (0:Wl 1:Wr 2:Ws1
// 3:We1); thread owns cols (2l, 2l+1). Per k: 1 coalesced float2 global
// read + 2 broadcast float4 LDS reads + 16 FMAs.
// ---------------------------------------------------------------------------
template<bool BF>
__device__ __forceinline__ void tok_body(
    const int* __restrict__ sent, const void* __restrict__ emb,
    const float* __restrict__ WTf,
    const void* __restrict__ bl,
    const void* __restrict__ bs1, const void* __restrict__ Ws2,
    const void* __restrict__ bs2,
    const void* __restrict__ be1, const void* __restrict__ We2,
    const void* __restrict__ be2,
    float* __restrict__ leftT, float* __restrict__ rightW,
    void* __restrict__ out, float (*sxT)[8], int* sids)
{
    const int tid = threadIdx.x;
    const int t0  = blockIdx.x * 8;

    if (tid < 8) sids[tid] = sent[t0 + tid];
    __syncthreads();

    // Stage 8 tokens token-minor: sxT[k][t] (scalar, ~16 lines/wave-load).
    for (int e = tid; e < DD * 8; e += 256) {
        int k = e >> 3, t = e & 7;
        sxT[k][t] = ld1<BF>(emb, sids[t] * DD + k);
    }
    __syncthreads();

    float a0[8], a1[8];                  // acc[token] for cols p0, p1
    #pragma unroll
    for (int t = 0; t < 8; ++t) { a0[t] = 0.f; a1[t] = 0.f; }

    const float* wp = WTf + 2 * tid;
    #pragma unroll 4
    for (int k = 0; k < DD; ++k) {
        float2 w  = *(const float2*)(wp + (size_t)k * NC);  // coalesced
        float4 xa = *(const float4*)&sxT[k][0];             // broadcasts
        float4 xb = *(const float4*)&sxT[k][4];
        a0[0] = fmaf(xa.x, w.x, a0[0]); a1[0] = fmaf(xa.x, w.y, a1[0]);
        a0[1] = fmaf(xa.y, w.x, a0[1]); a1[1] = fmaf(xa.y, w.y, a1[1]);
        a0[2] = fmaf(xa.z, w.x, a0[2]); a1[2] = fmaf(xa.z, w.y, a1[2]);
        a0[3] = fmaf(xa.w, w.x, a0[3]); a1[3] = fmaf(xa.w, w.y, a1[3]);
        a0[4] = fmaf(xb.x, w.x, a0[4]); a1[4] = fmaf(xb.x, w.y, a1[4]);
        a0[5] = fmaf(xb.y, w.x, a0[5]); a1[5] = fmaf(xb.y, w.y, a1[5]);
        a0[6] = fmaf(xb.z, w.x, a0[6]); a1[6] = fmaf(xb.z, w.y, a1[6]);
        a0[7] = fmaf(xb.w, w.x, a0[7]); a1[7] = fmaf(xb.w, w.y, a1[7]);
    }

    const int wv = tid >> 6;     // matrix id (wave-uniform)
    const int l  = tid & 63;
    const int p0 = 2 * l, p1 = p0 + 1;

    if (wv == 0) {               // left = x@Wl.T + bl -> leftT[b][p][j]
        float b0 = ld1<BF>(bl, p0), b1 = ld1<BF>(bl, p1);
        #pragma unroll
        for (int t = 0; t < 8; ++t) {
            int tg = t0 + t, bb = tg >> 8, jj = tg & 255;
            leftT[((size_t)bb * PP + p0) * NN + jj] = a0[t] + b0;
            leftT[((size_t)bb * PP + p1) * NN + jj] = a1[t] + b1;
        }
    } else if (wv == 1) {        // right = x@Wr.T -> rightW[t][p]
        #pragma unroll
        for (int t = 0; t < 8; ++t) {
            rightW[(size_t)(t0 + t) * PP + p0] = a0[t];
            rightW[(size_t)(t0 + t) * PP + p1] = a1[t];
        }
    } else {                     // start (wv==2) / end (wv==3) heads
        const void* h1 = (wv == 2) ? bs1 : be1;
        const void* h2 = (wv == 2) ? Ws2 : We2;
        const void* h3 = (wv == 2) ? bs2 : be2;
        float b0 = ld1<BF>(h1, p0), b1 = ld1<BF>(h1, p1);
        float w0 = ld1<BF>(h2, p0), w1 = ld1<BF>(h2, p1);
        float v[8];
        #pragma unroll
        for (int t = 0; t < 8; ++t)
            v[t] = fmaxf(a0[t] + b0, 0.f) * w0 + fmaxf(a1[t] + b1, 0.f) * w1;
        #pragma unroll
        for (int off = 32; off; off >>= 1) {
            #pragma unroll
            for (int t = 0; t < 8; ++t) v[t] += __shfl_down(v[t], off, 64);
        }
        if (l == 0) {
            float b2 = ld1<BF>(h3, 0);
            int base = (wv == 2) ? OFF_S : OFF_E;
            #pragma unroll
            for (int t = 0; t < 8; ++t)
                st1<BF>(out, base + t0 + t, v[t] + b2);
        }
    }
}

extern "C" __global__ void __launch_bounds__(256)
tok_kernel(const int* __restrict__ sent, const void* __restrict__ emb,
           const float* __restrict__ WTf,
           const void* __restrict__ bl,
           const void* __restrict__ bs1, const void* __restrict__ Ws2,
           const void* __restrict__ bs2,
           const void* __restrict__ be1, const void* __restrict__ We2,
           const void* __restrict__ be2,
           float* __restrict__ leftT, float* __restrict__ rightW,
           void* __restrict__ out, const int* __restrict__ flag)
{
    __shared__ __align__(16) float sxT[DD][8];
    __shared__ int sids[8];
    if (*flag) {
        tok_body<true >(sent, emb, WTf, bl, bs1, Ws2, bs2, be1, We2, be2,
                        leftT, rightW, out, sxT, sids);
    } else {
        tok_body<false>(sent, emb, WTf, bl, bs1, Ws2, bs2, be1, We2, be2,
                        leftT, rightW, out, sxT, sids);
    }
}

// ---------------------------------------------------------------------------
// Kernel B (verbatim from passing R2): bigram via thread=j, 4 i-accumulators.
// ---------------------------------------------------------------------------
extern "C" __global__ void __launch_bounds__(256)
big_kernel(const float* __restrict__ leftT, const float* __restrict__ rightW,
           const void* __restrict__ Wo, const void* __restrict__ bo,
           void* __restrict__ outB, const int* __restrict__ flag)
{
    __shared__ float sR[4][128];
    __shared__ float sWo[128];
    const int  tid = threadIdx.x;
    const int  b   = blockIdx.x >> 6;
    const int  i0  = (blockIdx.x & 63) << 2;
    const bool bf  = (*flag != 0);

    if (tid < 128) sWo[tid] = bf ? bf2f(((const u16*)Wo)[tid])
                                 : ((const float*)Wo)[tid];
    for (int c = tid; c < 512; c += 256) {
        int i = c >> 7, pp = c & 127;
        sR[i][pp] = rightW[((size_t)(b * NN + i0 + i)) * PP + pp];
    }
    __syncthreads();

    const int j = tid;
    const float* lp = leftT + (size_t)b * PP * NN + j;
    float acc0 = 0.f, acc1 = 0.f, acc2 = 0.f, acc3 = 0.f;
    #pragma unroll 8
    for (int pth = 0; pth < 128; ++pth) {
        float lv = lp[pth * NN];          // coalesced across j
        float wo = sWo[pth];
        acc0 = fmaf(fmaxf(lv + sR[0][pth], 0.f), wo, acc0);
        acc1 = fmaf(fmaxf(lv + sR[1][pth], 0.f), wo, acc1);
        acc2 = fmaf(fmaxf(lv + sR[2][pth], 0.f), wo, acc2);
        acc3 = fmaf(fmaxf(lv + sR[3][pth], 0.f), wo, acc3);
    }
    float bov = bf ? bf2f(((const u16*)bo)[0]) : ((const float*)bo)[0];
    size_t ob = ((size_t)(b * NN + i0)) * NN + j;
    if (bf) {
        u16* o = (u16*)outB;
        o[ob]          = f2bf(acc0 + bov);
        o[ob + NN]     = f2bf(acc1 + bov);
        o[ob + 2 * NN] = f2bf(acc2 + bov);
        o[ob + 3 * NN] = f2bf(acc3 + bov);
    } else {
        float* o = (float*)outB;
        o[ob]          = acc0 + bov;
        o[ob + NN]     = acc1 + bov;
        o[ob + 2 * NN] = acc2 + bov;
        o[ob + 3 * NN] = acc3 + bov;
    }
}

extern "C" void kernel_launch(void* const* d_in, const int* in_sizes, int n_in,
                              void* d_out, int out_size, void* d_ws, size_t ws_size,
                              hipStream_t stream) {
    const int*  sent = (const int*)d_in[0];
    const void* emb  = d_in[1];
    const void* Wl   = d_in[2];
    const void* bl   = d_in[3];
    const void* Wr   = d_in[4];
    const void* Wo   = d_in[5];
    const void* bo   = d_in[6];
    const void* Ws1  = d_in[7];
    const void* bs1  = d_in[8];
    const void* Ws2  = d_in[9];
    const void* bs2  = d_in[10];
    const void* We1  = d_in[11];
    const void* be1  = d_in[12];
    const void* We2  = d_in[13];
    const void* be2  = d_in[14];

    // ws layout: R2's exact prefix [flag 4B pad 1KB][leftT 1MB][rightW 1MB],
    // then WTf 300x512 f32 (600KB) appended.
    int*   flag   = (int*)d_ws;
    float* leftT  = (float*)((char*)d_ws + 1024);
    float* rightW = leftT + (size_t)NB * PP * NN;
    float* WTf    = rightW + (size_t)NB * NN * PP;

    hipLaunchKernelGGL(detect_kernel, dim3(1), dim3(64), 0, stream,
                       (const u32*)emb, flag);
    hipLaunchKernelGGL(prep_kernel, dim3(16), dim3(256), 0, stream,
                       Wl, Wr, Ws1, We1, WTf, flag);
    hipLaunchKernelGGL(tok_kernel, dim3(256), dim3(256), 0, stream,
                       sent, emb, WTf, bl, bs1, Ws2, bs2, be1, We2, be2,
                       leftT, rightW, d_out, flag);
    hipLaunchKernelGGL(big_kernel, dim3(512), dim3(256), 0, stream,
                       leftT, rightW, Wo, bo, d_out, flag);
}

// Round 8
// 158.772 us; speedup vs baseline: 1.2022x; 1.0316x over previous
//
#include <hip/hip_runtime.h>

// Problem constants: B=8, N=256, D=300, P=128, V=50001
#define NB 8
#define NN 256
#define DD 300
#define PP 128
#define NC 512                          // concat cols = [Wl|Wr|Ws1|We1]
#define OFF_S (NB * NN * NN)            // 524288  start-head element offset
#define OFF_E (NB * NN * NN + NB * NN)  // 526336  end-head element offset

typedef unsigned short u16;
typedef unsigned int   u32;

__device__ __forceinline__ float bf2f(u16 u) {
    union { u32 i; float f; } v;
    v.i = ((u32)u) << 16;
    return v.f;
}
__device__ __forceinline__ u16 f2bf(float f) {
    union { float f; u32 i; } v;
    v.f = f;
    u32 lsb = (v.i >> 16) & 1u;
    v.i += 0x7fffu + lsb;   // round-to-nearest-even
    return (u16)(v.i >> 16);
}

template<bool BF>
__device__ __forceinline__ float4 ld4(const void* base, int idx) {
    if (BF) {
        ushort4 e = *(const ushort4*)((const u16*)base + idx);
        return make_float4(bf2f(e.x), bf2f(e.y), bf2f(e.z), bf2f(e.w));
    } else {
        return *(const float4*)((const float*)base + idx);
    }
}
template<bool BF>
__device__ __forceinline__ float ld1(const void* base, int idx) {
    return BF ? bf2f(((const u16*)base)[idx]) : ((const float*)base)[idx];
}
template<bool BF>
__device__ __forceinline__ void st1(void* base, int idx, float v) {
    if (BF) ((u16*)base)[idx] = f2bf(v);
    else    ((float*)base)[idx] = v;
}
template<bool BF>
__device__ __forceinline__ void st4(void* base, int idx, float4 v) {
    if (BF) {
        ushort4 o = make_ushort4(f2bf(v.x), f2bf(v.y), f2bf(v.z), f2bf(v.w));
        *(ushort4*)((u16*)base + idx) = o;
    } else {
        *(float4*)((float*)base + idx) = v;
    }
}
// acc += relu(l + r) * w, componentwise over l (r, w scalar)
__device__ __forceinline__ float4 rfma4(float4 l, float r, float w, float4 a) {
    a.x = fmaf(fmaxf(l.x + r, 0.f), w, a.x);
    a.y = fmaf(fmaxf(l.y + r, 0.f), w, a.y);
    a.z = fmaf(fmaxf(l.z + r, 0.f), w, a.z);
    a.w = fmaf(fmaxf(l.w + r, 0.f), w, a.w);
    return a;
}

// ---------------------------------------------------------------------------
// Detector (verbatim from passing R2/R4/R7).
// ---------------------------------------------------------------------------
extern "C" __global__ void detect_kernel(const u32* __restrict__ embU,
                                         int* __restrict__ flag) {
    int lane = threadIdx.x;  // 64 threads
    int cnt = 0;
    for (int i = lane; i < 256; i += 64) {
        u32 w = embU[i];
        union { u32 u; float f; } v;
        v.u = (w & 0xFFFFu) << 16;
        float a = fabsf(v.f);
        if (a == 0.f || (a >= 0.00390625f && a <= 256.f)) cnt++;
    }
    #pragma unroll
    for (int off = 32; off; off >>= 1) cnt += __shfl_down(cnt, off, 64);
    if (lane == 0) *flag = (cnt >= 128) ? 1 : 0;
}

// ---------------------------------------------------------------------------
// prep (verbatim from passing R7): WTf[k][c] = (float)Wcat[c][k].
// ---------------------------------------------------------------------------
template<bool BF>
__device__ __forceinline__ void prep_body(
    const void* __restrict__ Wl, const void* __restrict__ Wr,
    const void* __restrict__ Ws1, const void* __restrict__ We1,
    float* __restrict__ WTf, float (*tile)[301])
{
    const int tid = threadIdx.x;
    const int c0  = blockIdx.x * 32;

    for (int e = tid; e < 32 * 75; e += 256) {       // row-major reads
        int r = e / 75;
        int q = e - r * 75;
        int c = c0 + r;
        const void* src = (c < 128) ? Wl : (c < 256) ? Wr
                        : (c < 384) ? Ws1 : We1;
        float4 f = ld4<BF>(src, (c & 127) * DD + 4 * q);
        tile[r][4 * q + 0] = f.x;
        tile[r][4 * q + 1] = f.y;
        tile[r][4 * q + 2] = f.z;
        tile[r][4 * q + 3] = f.w;
    }
    __syncthreads();
    for (int e = tid; e < 300 * 32; e += 256) {      // k-major writes
        int k = e >> 5;
        int c = e & 31;
        WTf[(size_t)k * NC + c0 + c] = tile[c][k];
    }
}

extern "C" __global__ void __launch_bounds__(256)
prep_kernel(const void* __restrict__ Wl, const void* __restrict__ Wr,
            const void* __restrict__ Ws1, const void* __restrict__ We1,
            float* __restrict__ WTf, const int* __restrict__ flag)
{
    __shared__ float tile[32][301];
    if (*flag) prep_body<true >(Wl, Wr, Ws1, We1, WTf, tile);
    else       prep_body<false>(Wl, Wr, Ws1, We1, WTf, tile);
}

// ---------------------------------------------------------------------------
// tok: R7-passing shape, split to 4 tokens/block (grid 512) for occupancy
// (2 blocks/CU, 2 waves/SIMD — halves the serial FMA chain per thread).
// Wave = matrix; thread owns cols (2l, 2l+1); per k: one coalesced float2
// weight read + one broadcast float4 LDS read + 8 FMAs.
// ---------------------------------------------------------------------------
template<bool BF>
__device__ __forceinline__ void tok_body(
    const int* __restrict__ sent, const void* __restrict__ emb,
    const float* __restrict__ WTf,
    const void* __restrict__ bl,
    const void* __restrict__ bs1, const void* __restrict__ Ws2,
    const void* __restrict__ bs2,
    const void* __restrict__ be1, const void* __restrict__ We2,
    const void* __restrict__ be2,
    float* __restrict__ leftT, float* __restrict__ rightW,
    void* __restrict__ out, float (*sxT)[4], int* sids)
{
    const int tid = threadIdx.x;
    const int t0  = blockIdx.x * 4;

    if (tid < 4) sids[tid] = sent[t0 + tid];
    __syncthreads();

    // Stage 4 tokens token-minor: sxT[k][t].
    for (int e = tid; e < DD * 4; e += 256) {
        int k = e >> 2, t = e & 3;
        sxT[k][t] = ld1<BF>(emb, sids[t] * DD + k);
    }
    __syncthreads();

    float a0[4], a1[4];                  // acc[token] for cols p0, p1
    #pragma unroll
    for (int t = 0; t < 4; ++t) { a0[t] = 0.f; a1[t] = 0.f; }

    const float* wp = WTf + 2 * tid;
    #pragma unroll 4
    for (int k = 0; k < DD; ++k) {
        float2 w  = *(const float2*)(wp + (size_t)k * NC);  // coalesced
        float4 xa = *(const float4*)&sxT[k][0];             // broadcast b128
        a0[0] = fmaf(xa.x, w.x, a0[0]); a1[0] = fmaf(xa.x, w.y, a1[0]);
        a0[1] = fmaf(xa.y, w.x, a0[1]); a1[1] = fmaf(xa.y, w.y, a1[1]);
        a0[2] = fmaf(xa.z, w.x, a0[2]); a1[2] = fmaf(xa.z, w.y, a1[2]);
        a0[3] = fmaf(xa.w, w.x, a0[3]); a1[3] = fmaf(xa.w, w.y, a1[3]);
    }

    const int wv = tid >> 6;     // matrix id (wave-uniform)
    const int l  = tid & 63;
    const int p0 = 2 * l, p1 = p0 + 1;

    if (wv == 0) {               // left = x@Wl.T + bl -> leftT[b][p][j]
        float b0 = ld1<BF>(bl, p0), b1 = ld1<BF>(bl, p1);
        #pragma unroll
        for (int t = 0; t < 4; ++t) {
            int tg = t0 + t, bb = tg >> 8, jj = tg & 255;
            leftT[((size_t)bb * PP + p0) * NN + jj] = a0[t] + b0;
            leftT[((size_t)bb * PP + p1) * NN + jj] = a1[t] + b1;
        }
    } else if (wv == 1) {        // right = x@Wr.T -> rightW[t][p]
        #pragma unroll
        for (int t = 0; t < 4; ++t) {
            rightW[(size_t)(t0 + t) * PP + p0] = a0[t];
            rightW[(size_t)(t0 + t) * PP + p1] = a1[t];
        }
    } else {                     // start (wv==2) / end (wv==3) heads
        const void* h1 = (wv == 2) ? bs1 : be1;
        const void* h2 = (wv == 2) ? Ws2 : We2;
        const void* h3 = (wv == 2) ? bs2 : be2;
        float b0 = ld1<BF>(h1, p0), b1 = ld1<BF>(h1, p1);
        float w0 = ld1<BF>(h2, p0), w1 = ld1<BF>(h2, p1);
        float v[4];
        #pragma unroll
        for (int t = 0; t < 4; ++t)
            v[t] = fmaxf(a0[t] + b0, 0.f) * w0 + fmaxf(a1[t] + b1, 0.f) * w1;
        #pragma unroll
        for (int off = 32; off; off >>= 1) {
            #pragma unroll
            for (int t = 0; t < 4; ++t) v[t] += __shfl_down(v[t], off, 64);
        }
        if (l == 0) {
            float b2 = ld1<BF>(h3, 0);
            int base = (wv == 2) ? OFF_S : OFF_E;
            #pragma unroll
            for (int t = 0; t < 4; ++t)
                st1<BF>(out, base + t0 + t, v[t] + b2);
        }
    }
}

extern "C" __global__ void __launch_bounds__(256)
tok_kernel(const int* __restrict__ sent, const void* __restrict__ emb,
           const float* __restrict__ WTf,
           const void* __restrict__ bl,
           const void* __restrict__ bs1, const void* __restrict__ Ws2,
           const void* __restrict__ bs2,
           const void* __restrict__ be1, const void* __restrict__ We2,
           const void* __restrict__ be2,
           float* __restrict__ leftT, float* __restrict__ rightW,
           void* __restrict__ out, const int* __restrict__ flag)
{
    __shared__ __align__(16) float sxT[DD][4];
    __shared__ int sids[4];
    if (*flag) {
        tok_body<true >(sent, emb, WTf, bl, bs1, Ws2, bs2, be1, We2, be2,
                        leftT, rightW, out, sxT, sids);
    } else {
        tok_body<false>(sent, emb, WTf, bl, bs1, Ws2, bs2, be1, We2, be2,
                        leftT, rightW, out, sxT, sids);
    }
}

// ---------------------------------------------------------------------------
// big v2: bigram[b,i,j] = sum_p relu(left[b,j,p]+right[b,i,p])*Wo[p] + bo.
// Grid 512 = (b in 8) x (64 i-tiles of 4). Block 256 thr = 4 waves.
// Lane owns j4 = 4 j's (float4 leftT reads, coalesced 1KB/wave); thread
// holds 4 i-accumulators (float4 each); wave w covers p-quarter
// [32w, 32w+32); cross-wave p-reduction through LDS at the end.
// Per thread: 32 global b128 + 40 LDS b128 + 1536 VALU (vs R2's 128
// scalar global + 640 scalar LDS).
// ---------------------------------------------------------------------------
template<bool BF>
__device__ __forceinline__ void big_body(
    const float* __restrict__ leftT, const float* __restrict__ rightW,
    const void* __restrict__ Wo, const void* __restrict__ bo,
    void* __restrict__ outB,
    float (*sR)[128], float* sWo, float4 (*red4)[64][4])
{
    const int tid = threadIdx.x;
    const int b   = blockIdx.x >> 6;
    const int i0  = (blockIdx.x & 63) << 2;

    if (tid < 128) sWo[tid] = ld1<BF>(Wo, tid);
    for (int c = tid; c < 512; c += 256) {
        int i = c >> 7, pp = c & 127;
        sR[i][pp] = rightW[((size_t)(b * NN + i0 + i)) * PP + pp];
    }
    __syncthreads();

    const int w    = tid >> 6;          // p-quarter
    const int lane = tid & 63;
    const int j4   = lane << 2;
    const float* lp = leftT + (size_t)b * PP * NN + j4;

    float4 A0 = {0.f, 0.f, 0.f, 0.f}, A1 = A0, A2 = A0, A3 = A0;
    const int pbase = w * 32;
    #pragma unroll
    for (int g = 0; g < 8; ++g) {
        const int p = pbase + g * 4;
        float4 wo = *(const float4*)&sWo[p];       // broadcast b128
        float4 r0 = *(const float4*)&sR[0][p];
        float4 r1 = *(const float4*)&sR[1][p];
        float4 r2 = *(const float4*)&sR[2][p];
        float4 r3 = *(const float4*)&sR[3][p];
        const float* lpp = lp + (size_t)p * NN;
        float4 l0 = *(const float4*)(lpp);         // coalesced b128
        float4 l1 = *(const float4*)(lpp + NN);
        float4 l2 = *(const float4*)(lpp + 2 * NN);
        float4 l3 = *(const float4*)(lpp + 3 * NN);
        A0 = rfma4(l0, r0.x, wo.x, A0);
        A1 = rfma4(l0, r1.x, wo.x, A1);
        A2 = rfma4(l0, r2.x, wo.x, A2);
        A3 = rfma4(l0, r3.x, wo.x, A3);
        A0 = rfma4(l1, r0.y, wo.y, A0);
        A1 = rfma4(l1, r1.y, wo.y, A1);
        A2 = rfma4(l1, r2.y, wo.y, A2);
        A3 = rfma4(l1, r3.y, wo.y, A3);
        A0 = rfma4(l2, r0.z, wo.z, A0);
        A1 = rfma4(l2, r1.z, wo.z, A1);
        A2 = rfma4(l2, r2.z, wo.z, A2);
        A3 = rfma4(l2, r3.z, wo.z, A3);
        A0 = rfma4(l3, r0.w, wo.w, A0);
        A1 = rfma4(l3, r1.w, wo.w, A1);
        A2 = rfma4(l3, r2.w, wo.w, A2);
        A3 = rfma4(l3, r3.w, wo.w, A3);
    }

    // Cross-wave p-reduction.
    red4[w][lane][0] = A0;
    red4[w][lane][1] = A1;
    red4[w][lane][2] = A2;
    red4[w][lane][3] = A3;
    __syncthreads();

    if (tid < 64) {
        float bov = ld1<BF>(bo, 0);
        #pragma unroll
        for (int i = 0; i < 4; ++i) {
            float4 s0 = red4[0][tid][i];
            float4 s1 = red4[1][tid][i];
            float4 s2 = red4[2][tid][i];
            float4 s3 = red4[3][tid][i];
            float4 s;
            s.x = s0.x + s1.x + s2.x + s3.x + bov;
            s.y = s0.y + s1.y + s2.y + s3.y + bov;
            s.z = s0.z + s1.z + s2.z + s3.z + bov;
            s.w = s0.w + s1.w + s2.w + s3.w + bov;
            st4<BF>(outB, (int)(((size_t)(b * NN + i0 + i)) * NN) + tid * 4, s);
        }
    }
}

extern "C" __global__ void __launch_bounds__(256)
big_kernel(const float* __restrict__ leftT, const float* __restrict__ rightW,
           const void* __restrict__ Wo, const void* __restrict__ bo,
           void* __restrict__ outB, const int* __restrict__ flag)
{
    __shared__ float sR[4][128];
    __shared__ float sWo[128];
    __shared__ float4 red4[4][64][4];
    if (*flag) big_body<true >(leftT, rightW, Wo, bo, outB, sR, sWo, red4);
    else       big_body<false>(leftT, rightW, Wo, bo, outB, sR, sWo, red4);
}

extern "C" void kernel_launch(void* const* d_in, const int* in_sizes, int n_in,
                              void* d_out, int out_size, void* d_ws, size_t ws_size,
                              hipStream_t stream) {
    const int*  sent = (const int*)d_in[0];
    const void* emb  = d_in[1];
    const void* Wl   = d_in[2];
    const void* bl   = d_in[3];
    const void* Wr   = d_in[4];
    const void* Wo   = d_in[5];
    const void* bo   = d_in[6];
    const void* Ws1  = d_in[7];
    const void* bs1  = d_in[8];
    const void* Ws2  = d_in[9];
    const void* bs2  = d_in[10];
    const void* We1  = d_in[11];
    const void* be1  = d_in[12];
    const void* We2  = d_in[13];
    const void* be2  = d_in[14];

    // ws layout (identical to passing R7): [flag 4B pad 1KB][leftT 1MB]
    // [rightW 1MB][WTf 300x512 f32]
    int*   flag   = (int*)d_ws;
    float* leftT  = (float*)((char*)d_ws + 1024);
    float* rightW = leftT + (size_t)NB * PP * NN;
    float* WTf    = rightW + (size_t)NB * NN * PP;

    hipLaunchKernelGGL(detect_kernel, dim3(1), dim3(64), 0, stream,
                       (const u32*)emb, flag);
    hipLaunchKernelGGL(prep_kernel, dim3(16), dim3(256), 0, stream,
                       Wl, Wr, Ws1, We1, WTf, flag);
    hipLaunchKernelGGL(tok_kernel, dim3(512), dim3(256), 0, stream,
                       sent, emb, WTf, bl, bs1, Ws2, bs2, be1, We2, be2,
                       leftT, rightW, d_out, flag);
    hipLaunchKernelGGL(big_kernel, dim3(512), dim3(256), 0, stream,
                       leftT, rightW, Wo, bo, d_out, flag);
}